// Round 7
// baseline (392.171 us; speedup 1.0000x reference)
//
#include <hip/hip_runtime.h>

typedef _Float16 f16;
typedef _Float16 f16x8 __attribute__((ext_vector_type(8)));
typedef __fp16   h16x2 __attribute__((ext_vector_type(2)));
typedef float    f32x4 __attribute__((ext_vector_type(4)));

constexpr int NB = 32, NN = 1024, KK = 1024, MO = 1024;
constexpr int BM = 128, BN = 128, BK = 64;
constexpr int LDA = 72;          // padded LDS row stride in f16 (144 B)
constexpr int NSTEP = KK / BK;   // 16

// History (measured, rocprof dur):
//   (256,2) BK=32 dbuf dist-2:            196 us  <- all pipes idle, latency-bound
//   (256,3)/(256,4): REGRESS (spill; gfx950 unified VGPR/AGPR file, acc counts)
//   lgkm-only barrier (drop vmcnt drain): 196 us  <- NEUTRAL: reg-dep waits were
//            already non-blocking at prefetch distance 2. Limit = fixed per-step
//            overhead (barrier lockstep + ds latency chain) at 3675 cyc/step vs
//            ~1.5-2.5k cyc of work. => amortize: BK 32->64, 32 steps -> 16.
// LDS 73728 B/block -> 2 blocks/CU (147 KB <= 160 KB). Regs ~185 <= 256: no spill.
__global__ __launch_bounds__(256, 2)
void cond_linear_kernel(const float* __restrict__ x,
                        const int* __restrict__ task_id,
                        const float* __restrict__ W,
                        float* __restrict__ out) {
    __shared__ __align__(16) f16 As[2][BM * LDA];
    __shared__ __align__(16) f16 Bs[2][BN * LDA];

    const int bid   = blockIdx.x;
    const int batch = bid >> 6;
    const int tile  = bid & 63;
    // XCD swizzle: bid%8 == tile&7 == tm -> all 8 tn-tiles sharing an x-band
    // land on the same XCD's L2 (round-robin dispatch assumption; perf-only).
    const int tm = tile & 7;
    const int tn = tile >> 3;

    const int tid  = threadIdx.x;
    const int task = task_id[batch];

    const float* xb = x + (size_t)batch * NN * KK + (size_t)(tm * BM) * KK;
    const float* wb = W + (size_t)task * MO * KK + (size_t)(tn * BN) * KK;

    // staging (BK=64): per matrix 128x64 floats = 1024 chunks of 8 floats;
    // 256 threads -> 4 chunks each at rows r0+{0,32,64,96}, fixed ko.
    const int r0 = tid >> 3;          // 0..31
    const int ko = (tid & 7) * 8;     // 0..56

    const float* pa = xb + (size_t)r0 * KK + ko;
    const float* pb = wb + (size_t)r0 * KK + ko;

    // single register slot in flight (prefetch distance 1): 16 f32x4 = 64 VGPR
    f32x4 ra[8], rb[8];

    auto load = [&](int k0) {
        #pragma unroll
        for (int m = 0; m < 4; ++m) {
            ra[2 * m]     = *(const f32x4*)(pa + (size_t)m * 32 * KK + k0);
            ra[2 * m + 1] = *(const f32x4*)(pa + (size_t)m * 32 * KK + k0 + 4);
            rb[2 * m]     = *(const f32x4*)(pb + (size_t)m * 32 * KK + k0);
            rb[2 * m + 1] = *(const f32x4*)(pb + (size_t)m * 32 * KK + k0 + 4);
        }
    };

    auto cvt8 = [](const f32x4& lo, const f32x4& hi) -> f16x8 {
        union { h16x2 h[4]; f16x8 v; } u;
        u.h[0] = __builtin_amdgcn_cvt_pkrtz(lo[0], lo[1]);
        u.h[1] = __builtin_amdgcn_cvt_pkrtz(lo[2], lo[3]);
        u.h[2] = __builtin_amdgcn_cvt_pkrtz(hi[0], hi[1]);
        u.h[3] = __builtin_amdgcn_cvt_pkrtz(hi[2], hi[3]);
        return u.v;
    };

    auto store = [&](int buf) {
        #pragma unroll
        for (int m = 0; m < 4; ++m) {
            *(f16x8*)&As[buf][(r0 + m * 32) * LDA + ko] = cvt8(ra[2 * m], ra[2 * m + 1]);
            *(f16x8*)&Bs[buf][(r0 + m * 32) * LDA + ko] = cvt8(rb[2 * m], rb[2 * m + 1]);
        }
    };

    // LDS-only barrier: in-flight global loads (private reg dests) legally
    // cross; reg-dependency vmcnt(N) before their use preserves correctness.
    auto lds_barrier = [] {
        asm volatile("s_waitcnt lgkmcnt(0)" ::: "memory");
        __builtin_amdgcn_s_barrier();
    };

    // wave layout: 2x2 waves, each 64x64 via 4x4 MFMA 16x16 tiles
    const int lane = tid & 63;
    const int wave = tid >> 6;
    const int wr   = (wave >> 1) * 64;
    const int wc   = (wave & 1) * 64;
    const int lm   = lane & 15;
    const int lq   = lane >> 4;

    f32x4 acc[4][4] = {};

    const int fa_off = (wr + lm) * LDA + lq * 8;
    const int fb_off = (wc + lm) * LDA + lq * 8;

    // BK=64: two K=32 halves per step (kh selects +0/+32 within the row)
    auto compute = [&](int buf) {
        #pragma unroll
        for (int kh = 0; kh < 2; ++kh) {
            f16x8 af[4], bf[4];
            #pragma unroll
            for (int i = 0; i < 4; ++i) af[i] = *(const f16x8*)&As[buf][fa_off + i * 16 * LDA + kh * 32];
            #pragma unroll
            for (int j = 0; j < 4; ++j) bf[j] = *(const f16x8*)&Bs[buf][fb_off + j * 16 * LDA + kh * 32];
            #pragma unroll
            for (int i = 0; i < 4; ++i)
                #pragma unroll
                for (int j = 0; j < 4; ++j)
                    acc[i][j] = __builtin_amdgcn_mfma_f32_16x16x32_f16(af[i], bf[j], acc[i][j], 0, 0, 0);
        }
    };

    // prologue: stage step 0 into buf0
    load(0);
    store(0);
    lds_barrier();

    // steady state: issue G(ks+1); compute buf ks&1 (hides load latency);
    // stage G(ks+1) into the other buffer; single lgkm-only barrier.
    // Buffer (ks+1)&1 was last read in iteration ks-1 -> barrier-protected.
    for (int ks = 0; ks < NSTEP; ks += 2) {
        load(1 * BK + ks * BK);
        compute(0);
        store(1);
        lds_barrier();
        if (ks + 2 < NSTEP) load((ks + 2) * BK);
        compute(1);
        if (ks + 2 < NSTEP) store(0);
        lds_barrier();
    }

    // epilogue: C/D layout col=lane&15, row=(lane>>4)*4+reg  [m89-verified]
    float* ob = out + (size_t)batch * NN * MO + (size_t)(tm * BM) * MO + (tn * BN);
    #pragma unroll
    for (int i = 0; i < 4; ++i) {
        #pragma unroll
        for (int j = 0; j < 4; ++j) {
            const int row0 = wr + i * 16 + lq * 4;
            const int col  = wc + j * 16 + lm;
            #pragma unroll
            for (int r = 0; r < 4; ++r)
                ob[(size_t)(row0 + r) * MO + col] = acc[i][j][r];
        }
    }

    // second tuple output: task_id as float, at offset NB*NN*MO
    if (tile == 0 && tid == 0)
        out[(size_t)NB * NN * MO + batch] = (float)task;
}

extern "C" void kernel_launch(void* const* d_in, const int* in_sizes, int n_in,
                              void* d_out, int out_size, void* d_ws, size_t ws_size,
                              hipStream_t stream) {
    const float* x       = (const float*)d_in[0];
    const int*   task_id = (const int*)d_in[1];
    const float* W       = (const float*)d_in[2];
    float*       out     = (float*)d_out;

    dim3 grid(NB * (NN / BM) * (MO / BN));  // 2048
    dim3 block(256);
    cond_linear_kernel<<<grid, block, 0, stream>>>(x, task_id, W, out);
}